// Round 8
// baseline (1268.919 us; speedup 1.0000x reference)
//
#include <hip/hip_runtime.h>
#include <hip/hip_bf16.h>
#include <hip/hip_fp16.h>

typedef unsigned short u16;
typedef unsigned int u32;
typedef __attribute__((ext_vector_type(8))) _Float16 f16x8;
typedef __attribute__((ext_vector_type(4))) float f32x4;

#define RSTR 12          // red stride in floats (16B-aligned, 4 waves x {s,t} + pad)

__device__ __forceinline__ float bf2f(u16 b) {
  union { u32 u; float f; } c; c.u = ((u32)b) << 16; return c.f;
}
__device__ __forceinline__ u16 f2bf(float f) {
  union { float f; u32 u; } c; c.f = f;
  u32 r = c.u + 0x7FFFu + ((c.u >> 16) & 1u);
  return (u16)(r >> 16);
}
__device__ __forceinline__ float gelu_tanh(float x) {
  // tanh-form gelu == x * sigmoid(2*0.79788456*(x + 0.044715 x^3))
  float x2 = x * x;
  float t = __builtin_fmaf(0.044715f, x2, 1.0f);
  float e = __expf(-1.5957691216057308f * (x * t));
  return x * __builtin_amdgcn_rcpf(1.f + e);
}
// load a scalar param that may be fp32 or bf16
__device__ __forceinline__ float ldp(const void* p, int i, int f32) {
  return f32 ? ((const float*)p)[i] : bf2f(((const u16*)p)[i]);
}
// load 4 consecutive params (fp32 or bf16) vectorized
__device__ __forceinline__ f32x4 load4p(const void* p, int i, int f32) {
  if (f32) return *(const f32x4*)((const float*)p + i);
  ushort4 u = *(const ushort4*)((const u16*)p + i);
  return (f32x4){bf2f(u.x), bf2f(u.y), bf2f(u.z), bf2f(u.w)};
}
// load 8 consecutive elements (fp32 or bf16) as f16x8 (vectorized)
__device__ __forceinline__ f16x8 load8(const void* base, long off, int f32) {
  f16x8 r;
  if (f32) {
    const float4* p = (const float4*)((const float*)base + off);
    float4 a = p[0], b = p[1];
    r[0] = (_Float16)a.x; r[1] = (_Float16)a.y; r[2] = (_Float16)a.z; r[3] = (_Float16)a.w;
    r[4] = (_Float16)b.x; r[5] = (_Float16)b.y; r[6] = (_Float16)b.z; r[7] = (_Float16)b.w;
  } else {
    const u16* p = (const u16*)base + off;
#pragma unroll
    for (int i = 0; i < 8; ++i) r[i] = (_Float16)bf2f(p[i]);
  }
  return r;
}
// monotone (sortable) encoding of fp16 bit patterns, and decode-to-f32
__device__ __forceinline__ u32 encH(u32 h) {
  return (h & 0x8000u) ? (h ^ 0xFFFFu) : (h | 0x8000u);
}
__device__ __forceinline__ float decE(u32 e) {
  u32 h = (e & 0x8000u) ? (e & 0x7FFFu) : (~e & 0xFFFFu);
  return __half2float(__ushort_as_half((u16)h));
}
__device__ __forceinline__ u32 umin32(u32 a, u32 b) { return a < b ? a : b; }
__device__ __forceinline__ u32 umax32(u32 a, u32 b) { return a > b ? a : b; }

// one wave: decide whether inputs are fp32 (flag=1) or bf16 (flag=0).
__global__ void detect_dtype(const u16* __restrict__ obs, int* flag) {
  int l = threadIdx.x;
  float v = fabsf(bf2f(obs[2 * l]));
  if (v != v) v = 1e30f;  // NaN pattern also implies fp32
#pragma unroll
  for (int m = 1; m <= 32; m <<= 1) v = fmaxf(v, __shfl_xor(v, m, 64));
  if (l == 0) *flag = (v > 1000.0f) ? 1 : 0;
}

// Pack W [K x 512] into MFMA-fragment-major order (fp16):
// dst[((w*4+ci)*nk + t)*512 + lane*8 + j] = W[k][ch],
//   ch = w*64 + ci*16 + (lane&15), k = t*32 + (lane>>4)*8 + j.
// (unchanged layout; the main kernel's wave->channel remap indexes into it)
__global__ void pack_frag(const void* __restrict__ src, u16* __restrict__ dst,
                          const int* __restrict__ flag, int total,
                          int fshift, int cishift, int tmask) {
  int id = blockIdx.x * 256 + threadIdx.x;
  if (id >= total) return;
  int j = id & 7;
  int lane = (id >> 3) & 63;
  int fi = id >> 9;
  int w = fi >> fshift;
  int rem = fi & ((1 << fshift) - 1);
  int ci = rem >> cishift;
  int t = rem & tmask;
  int q = lane >> 4, r = lane & 15;
  int ch = w * 64 + ci * 16 + r;
  int k = t * 32 + q * 8 + j;
  float v = ldp(src, k * 512 + ch, *flag);
  dst[id] = __half_as_ushort(__float2half(v));
}

// 256 threads = 4 waves; 8 s/g pairs (16 rows) per block; wave owns 128 channels.
// 5 blocks/CU target (20 waves/CU): regs <= 102 via launch_bounds(256,5),
// LDS = 16KB slab + 768B red. All activations (incl. layer-3 phi) live in slab
// with ONE frag-major layout; IQE reads frag-major directly.
__global__ __launch_bounds__(256, 5) void gciqe_main(
    const void* __restrict__ obs, const void* __restrict__ goals,
    const u16* __restrict__ wT0, const u16* __restrict__ wT1,
    const u16* __restrict__ wT2, const u16* __restrict__ wT3,
    const void* __restrict__ b0, const void* __restrict__ b1,
    const void* __restrict__ b2, const void* __restrict__ b3,
    const void* __restrict__ ls0, const void* __restrict__ lb0,
    const void* __restrict__ ls1, const void* __restrict__ lb1,
    const void* __restrict__ ls2, const void* __restrict__ lb2,
    const void* __restrict__ alphap, void* __restrict__ out,
    const int* __restrict__ flagp)
{
  // frag f = (channel>>5): value(row, ch) at slab[f*512 + ((ch>>3&3)*16+row)*8 + (ch&7)]
  __shared__ __align__(16) u16 slab[16 * 512];
  __shared__ __align__(16) float red[16 * RSTR];  // LN partials [row][wave]{s,t}

  const int f32 = *flagp;
  const int tid = threadIdx.x;
  const int lane = tid & 63, w2 = tid >> 6;     // 4 waves = 4 groups of 128 ch
  const int r = lane & 15, q = lane >> 4;
  const int i0 = blockIdx.x * 8;                // 8 pairs per block

  f32x4 acc[8];                                 // one f32x4 per 16-ch group (32 AGPR)

  // ---------------- layer 0: [16 x 64] @ W0 -> acc ----------------
#pragma unroll
  for (int c8 = 0; c8 < 8; ++c8) acc[c8] = (f32x4){0.f, 0.f, 0.f, 0.f};
  {
    f16x8 bf0[2];
    const void* base = (r & 1) ? goals : obs;   // row r: pair r>>1, even=obs
    long ro = (long)(i0 + (r >> 1)) * 64;
#pragma unroll
    for (int u = 0; u < 2; ++u)
      bf0[u] = load8(base, ro + u * 32 + q * 8, f32);
#pragma unroll
    for (int c8 = 0; c8 < 8; ++c8) {
#pragma unroll
      for (int u = 0; u < 2; ++u) {
        // layer0 frag for (ch-group c8, k-chunk u): pack idx (w2*16 + c8*2 + u)
        f16x8 af = *(const f16x8*)(wT0 + (w2 * 16 + c8 * 2 + u) * 512 + lane * 8);
        acc[c8] = __builtin_amdgcn_mfma_f32_16x16x32_f16(af, bf0[u], acc[c8], 0, 0, 0);
      }
    }
  }

  // ---------------- layers 0..2 epilogue + layers 1..3 GEMM ----------------
  for (int l = 0; l <= 3; ++l) {
    if (l > 0) {
      const u16* wp = (l == 1) ? wT1 : (l == 2) ? wT2 : wT3;
      // frag (c8, t) at wp + (w2*128 + c8*16 + t)*512
      const u16* wbase = wp + w2 * 65536;
#pragma unroll
      for (int c8 = 0; c8 < 8; ++c8) acc[c8] = (f32x4){0.f, 0.f, 0.f, 0.f};
      f16x8 A[2][4], Br[2];
      // prologue: step 0 = (t=0, h=0): c8 = 0..3, t = 0
#pragma unroll
      for (int u2 = 0; u2 < 4; ++u2)
        A[0][u2] = *(const f16x8*)(wbase + (u2 * 16 + 0) * 512 + lane * 8);
      Br[0] = *(const f16x8*)(slab + 0 * 512 + lane * 8);
#pragma unroll
      for (int t = 0; t < 16; ++t) {
        if (t < 15)
          Br[(t + 1) & 1] = *(const f16x8*)(slab + (t + 1) * 512 + lane * 8);
#pragma unroll
        for (int h = 0; h < 2; ++h) {
          const int s = t * 2 + h;
          if (s < 31) {
            const int s1 = s + 1, t1 = s1 >> 1, h1 = s1 & 1;
#pragma unroll
            for (int u2 = 0; u2 < 4; ++u2)
              A[s1 & 1][u2] = *(const f16x8*)(wbase + ((h1 * 4 + u2) * 16 + t1) * 512 + lane * 8);
          }
#pragma unroll
          for (int u2 = 0; u2 < 4; ++u2)
            acc[h * 4 + u2] = __builtin_amdgcn_mfma_f32_16x16x32_f16(
                A[s & 1][u2], Br[t & 1], acc[h * 4 + u2], 0, 0, 0);
        }
      }
    }

    if (l < 3) {
      // ---- bias + gelu + LayerNorm -> frag-major slab (fp16) ----
      const void* pb  = (l == 0) ? b0 : (l == 1) ? b1 : b2;
      const void* psl = (l == 0) ? ls0 : (l == 1) ? ls1 : ls2;
      const void* plb = (l == 0) ? lb0 : (l == 1) ? lb1 : lb2;
      float s_ = 0.f, t_ = 0.f;
#pragma unroll
      for (int c8 = 0; c8 < 8; ++c8) {
        int cb = w2 * 128 + c8 * 16 + q * 4;
        f32x4 bb = load4p(pb, cb, f32);
        f32x4 v = acc[c8];
        v.x = gelu_tanh(v.x + bb.x); v.y = gelu_tanh(v.y + bb.y);
        v.z = gelu_tanh(v.z + bb.z); v.w = gelu_tanh(v.w + bb.w);
        acc[c8] = v;
        s_ += v.x + v.y + v.z + v.w;
        t_ += v.x * v.x + v.y * v.y + v.z * v.z + v.w * v.w;
      }
      s_ += __shfl_xor(s_, 16, 64); t_ += __shfl_xor(t_, 16, 64);
      s_ += __shfl_xor(s_, 32, 64); t_ += __shfl_xor(t_, 32, 64);
      if (q == 0)
        *(float2*)(red + r * RSTR + w2 * 2) = make_float2(s_, t_);
      __syncthreads();   // red visible + all slab reads done before writes below
      float ts = 0.f, tq = 0.f;
#pragma unroll
      for (int p = 0; p < 2; ++p) {
        f32x4 a = *(const f32x4*)(red + r * RSTR + p * 4);
        ts += a.x + a.z; tq += a.y + a.w;
      }
      const float mean = ts * (1.f / 512.f);
      const float rstd = rsqrtf(tq * (1.f / 512.f) - mean * mean + 1e-6f);
#pragma unroll
      for (int c8 = 0; c8 < 8; ++c8) {
        int cb = w2 * 128 + c8 * 16 + q * 4;
        f32x4 gg = load4p(psl, cb, f32);
        f32x4 hh = load4p(plb, cb, f32);
        // LN as single fma per value: v*rg + (h - mean*rg)
        f32x4 rg, bp;
        rg.x = rstd * gg.x; rg.y = rstd * gg.y; rg.z = rstd * gg.z; rg.w = rstd * gg.w;
        bp.x = hh.x - mean * rg.x; bp.y = hh.y - mean * rg.y;
        bp.z = hh.z - mean * rg.z; bp.w = hh.w - mean * rg.w;
        f32x4 v = acc[c8];
        ushort4 o;
        o.x = __half_as_ushort(__float2half(v.x * rg.x + bp.x));
        o.y = __half_as_ushort(__float2half(v.y * rg.y + bp.y));
        o.z = __half_as_ushort(__float2half(v.z * rg.z + bp.z));
        o.w = __half_as_ushort(__float2half(v.w * rg.w + bp.w));
        // frag-major store (inverse of GEMM-B read): fk = cb>>5
        int fk = w2 * 4 + (c8 >> 1);
        int sub = ((c8 & 1) * 2 + (q >> 1)) * 128 + r * 8 + (q & 1) * 4;
        *(ushort4*)(slab + fk * 512 + sub) = o;
      }
      __syncthreads();
    } else {
      // ---- layer 3: bias only; SAME frag-major store (no layout change) ----
      __syncthreads();   // all waves done GEMM-reading slab before overwrite
#pragma unroll
      for (int c8 = 0; c8 < 8; ++c8) {
        int cb = w2 * 128 + c8 * 16 + q * 4;
        f32x4 bb = load4p(b3, cb, f32);
        f32x4 v = acc[c8];
        ushort4 o;
        o.x = __half_as_ushort(__float2half(v.x + bb.x));
        o.y = __half_as_ushort(__float2half(v.y + bb.y));
        o.z = __half_as_ushort(__float2half(v.z + bb.z));
        o.w = __half_as_ushort(__float2half(v.w + bb.w));
        int fk = w2 * 4 + (c8 >> 1);
        int sub = ((c8 & 1) * 2 + (q >> 1)) * 128 + r * 8 + (q & 1) * 4;
        *(ushort4*)(slab + fk * 512 + sub) = o;
      }
      __syncthreads();   // phi (frag-major) visible before IQE reads
    }
  }

  // ---------------- IQE head (packed u32 key|payload bitonic) ----------------
  {
    const float al = ldp(alphap, 0, f32);
    const float aa = 1.f / (1.f + __expf(-al));
    const int h = lane >> 5, il = lane & 31;    // two components per wave pass
#pragma unroll
    for (int pv = 0; pv < 2; ++pv) {
      int pL = 2 * w2 + pv;                     // block-local pair 0..7
      float cs = 0.f, cm = 0.f;
      for (int it = 0; it < 8; ++it) {
        int c = 2 * it + h;                     // component 0..15
        // frag-major phi read: value(row, ch=c*32+il) at
        // slab[c*512 + (il>>3)*128 + row*8 + (il&7)]; rows 2pL / 2pL+1
        int ba = c * 512 + (il >> 3) * 128 + pL * 16 + (il & 7);
        u32 xh = slab[ba];
        u32 yh = slab[ba + 8];
        u32 ex = encH(xh), ey = encH(yh);
        // invalid interval (!(x<y)) -> y = -inf encoding (0x03FF)
        u32 sv = (ex << 16) | ((ex < ey) ? ey : 0x03FFu);
        // bitonic ascending sort of packed (x|y) across each 32-lane half
#pragma unroll
        for (int k = 2; k <= 32; k <<= 1)
#pragma unroll
          for (int j = k >> 1; j >= 1; j >>= 1) {
            u32 so = __shfl_xor(sv, j, 64);
            u32 mn = umin32(sv, so), mx = umax32(sv, so);
            bool up = ((il & k) == 0) == ((il & j) == 0);
            sv = up ? mn : mx;
          }
        // exclusive prefix-max of encoded y in start-sorted order
        u32 ye = sv & 0xFFFFu;
        u32 p = __shfl_up(ye, 1, 32);
        if (il == 0) p = 0u;
#pragma unroll
        for (int d = 1; d <= 16; d <<= 1) {
          u32 t2 = __shfl_up(p, d, 32);
          if (il >= d) p = umax32(p, t2);
        }
        float contrib = fmaxf(0.f, decE(ye) - decE(umax32(sv >> 16, p)));
#pragma unroll
        for (int msk = 1; msk <= 16; msk <<= 1)
          contrib += __shfl_xor(contrib, msk, 64);
        cs += contrib;
        cm = fmaxf(cm, contrib);
      }
      cs += __shfl_xor(cs, 32, 64);
      cm = fmaxf(cm, __shfl_xor(cm, 32, 64));
      if (lane == 0) {
        float res = aa * (cs * (1.f / 16.f)) + (1.f - aa) * cm;
        if (f32) ((float*)out)[i0 + pL] = res;
        else ((u16*)out)[i0 + pL] = f2bf(res);
      }
    }
  }
}

extern "C" void kernel_launch(void* const* d_in, const int* in_sizes, int n_in,
                              void* d_out, int out_size, void* d_ws, size_t ws_size,
                              hipStream_t stream) {
  (void)in_sizes; (void)n_in; (void)out_size; (void)ws_size;
  const void* obs   = d_in[0];
  const void* goals = d_in[1];
  const void* W0 = d_in[2];
  const void* b0 = d_in[3];
  const void* ls0 = d_in[4];
  const void* lb0 = d_in[5];
  const void* W1 = d_in[6];
  const void* b1 = d_in[7];
  const void* ls1 = d_in[8];
  const void* lb1 = d_in[9];
  const void* W2 = d_in[10];
  const void* b2 = d_in[11];
  const void* ls2 = d_in[12];
  const void* lb2 = d_in[13];
  const void* W3 = d_in[14];
  const void* b3 = d_in[15];
  const void* alpha = d_in[16];

  int* flag = (int*)d_ws;
  u16* wT0 = (u16*)((char*)d_ws + 64);
  u16* wT1 = wT0 + 512 * 64;
  u16* wT2 = wT1 + 512 * 512;
  u16* wT3 = wT2 + 512 * 512;

  detect_dtype<<<1, 64, 0, stream>>>((const u16*)obs, flag);
  // layer0: K=64, nk=2: fshift=3 (4*nk=8 frags/wave), cishift=1, tmask=1
  pack_frag<<<128, 256, 0, stream>>>(W0, wT0, flag, 512 * 64, 3, 1, 1);
  // layers1-3: K=512, nk=16: fshift=6 (64 frags/wave), cishift=4, tmask=15
  pack_frag<<<1024, 256, 0, stream>>>(W1, wT1, flag, 512 * 512, 6, 4, 15);
  pack_frag<<<1024, 256, 0, stream>>>(W2, wT2, flag, 512 * 512, 6, 4, 15);
  pack_frag<<<1024, 256, 0, stream>>>(W3, wT3, flag, 512 * 512, 6, 4, 15);
  // 131072 pairs / 8 pairs-per-block = 16384 blocks of 256 threads
  gciqe_main<<<16384, 256, 0, stream>>>(obs, goals, wT0, wT1, wT2, wT3,
      b0, b1, b2, b3, ls0, lb0, ls1, lb1, ls2, lb2, alpha, d_out, flag);
}

// Round 11
// 921.944 us; speedup vs baseline: 1.3764x; 1.3764x over previous
//
#include <hip/hip_runtime.h>
#include <hip/hip_bf16.h>
#include <hip/hip_fp16.h>

typedef unsigned short u16;
typedef unsigned int u32;
typedef __attribute__((ext_vector_type(8))) _Float16 f16x8;
typedef __attribute__((ext_vector_type(4))) float f32x4;

#define ROWS 32          // 16 s/g pairs per block
#define RSTR 20          // red stride in floats (16B-aligned, bank-spread)
#define PSTR 520         // phi row stride in u16

__device__ __forceinline__ float bf2f(u16 b) {
  union { u32 u; float f; } c; c.u = ((u32)b) << 16; return c.f;
}
__device__ __forceinline__ u16 f2bf(float f) {
  union { float f; u32 u; } c; c.f = f;
  u32 r = c.u + 0x7FFFu + ((c.u >> 16) & 1u);
  return (u16)(r >> 16);
}
__device__ __forceinline__ float gelu_tanh(float x) {
  // tanh-form gelu == x * sigmoid(2*0.79788456*(x + 0.044715 x^3))
  float x2 = x * x;
  float t = __builtin_fmaf(0.044715f, x2, 1.0f);
  float e = __expf(-1.5957691216057308f * (x * t));
  return x * __builtin_amdgcn_rcpf(1.f + e);
}
// load a scalar param that may be fp32 or bf16
__device__ __forceinline__ float ldp(const void* p, int i, int f32) {
  return f32 ? ((const float*)p)[i] : bf2f(((const u16*)p)[i]);
}
// load 4 consecutive params (fp32 or bf16) vectorized
__device__ __forceinline__ f32x4 load4p(const void* p, int i, int f32) {
  if (f32) return *(const f32x4*)((const float*)p + i);
  ushort4 u = *(const ushort4*)((const u16*)p + i);
  return (f32x4){bf2f(u.x), bf2f(u.y), bf2f(u.z), bf2f(u.w)};
}
// load 8 consecutive elements (fp32 or bf16) as f16x8 (vectorized)
__device__ __forceinline__ f16x8 load8(const void* base, long off, int f32) {
  f16x8 r;
  if (f32) {
    const float4* p = (const float4*)((const float*)base + off);
    float4 a = p[0], b = p[1];
    r[0] = (_Float16)a.x; r[1] = (_Float16)a.y; r[2] = (_Float16)a.z; r[3] = (_Float16)a.w;
    r[4] = (_Float16)b.x; r[5] = (_Float16)b.y; r[6] = (_Float16)b.z; r[7] = (_Float16)b.w;
  } else {
    const u16* p = (const u16*)base + off;
#pragma unroll
    for (int i = 0; i < 8; ++i) r[i] = (_Float16)bf2f(p[i]);
  }
  return r;
}
// monotone (sortable) encoding of fp16 bit patterns, and decode-to-f32
__device__ __forceinline__ u32 encH(u32 h) {
  return (h & 0x8000u) ? (h ^ 0xFFFFu) : (h | 0x8000u);
}
__device__ __forceinline__ float decE(u32 e) {
  u32 h = (e & 0x8000u) ? (e & 0x7FFFu) : (~e & 0xFFFFu);
  return __half2float(__ushort_as_half((u16)h));
}
__device__ __forceinline__ u32 umin32(u32 a, u32 b) { return a < b ? a : b; }
__device__ __forceinline__ u32 umax32(u32 a, u32 b) { return a > b ? a : b; }

// one wave: decide whether inputs are fp32 (flag=1) or bf16 (flag=0).
__global__ void detect_dtype(const u16* __restrict__ obs, int* flag) {
  int l = threadIdx.x;
  float v = fabsf(bf2f(obs[2 * l]));
  if (v != v) v = 1e30f;  // NaN pattern also implies fp32
#pragma unroll
  for (int m = 1; m <= 32; m <<= 1) v = fmaxf(v, __shfl_xor(v, m, 64));
  if (l == 0) *flag = (v > 1000.0f) ? 1 : 0;
}

// Pack W [K x 512] into MFMA-fragment-major order (fp16):
// dst[((w*4+ci)*nk + t)*512 + lane*8 + j] = W[k][ch],
//   ch = w*64 + ci*16 + (lane&15), k = t*32 + (lane>>4)*8 + j.
__global__ void pack_frag(const void* __restrict__ src, u16* __restrict__ dst,
                          const int* __restrict__ flag, int total,
                          int fshift, int cishift, int tmask) {
  int id = blockIdx.x * 256 + threadIdx.x;
  if (id >= total) return;
  int j = id & 7;
  int lane = (id >> 3) & 63;
  int fi = id >> 9;
  int w = fi >> fshift;
  int rem = fi & ((1 << fshift) - 1);
  int ci = rem >> cishift;
  int t = rem & tmask;
  int q = lane >> 4, r = lane & 15;
  int ch = w * 64 + ci * 16 + r;
  int k = t * 32 + q * 8 + j;
  float v = ldp(src, k * 512 + ch, *flag);
  dst[id] = __half_as_ushort(__float2half(v));
}

__global__ __launch_bounds__(512, 4) void gciqe_main(
    const void* __restrict__ obs, const void* __restrict__ goals,
    const u16* __restrict__ wT0, const u16* __restrict__ wT1,
    const u16* __restrict__ wT2, const u16* __restrict__ wT3,
    const void* __restrict__ b0, const void* __restrict__ b1,
    const void* __restrict__ b2, const void* __restrict__ b3,
    const void* __restrict__ ls0, const void* __restrict__ lb0,
    const void* __restrict__ ls1, const void* __restrict__ lb1,
    const void* __restrict__ ls2, const void* __restrict__ lb2,
    const void* __restrict__ alphap, void* __restrict__ out,
    const int* __restrict__ flagp)
{
  // slab: layers 0..2 activations, FRAGMENT-MAJOR only (frag f = nt*16+kq*4+u,
  // 32 frags x 512 u16). GEMM reads are slab + f*512 + lane*8: conflict-free.
  // phi: dedicated row-major [32][PSTR] buffer for layer-3 output (IQE input).
  __shared__ __align__(16) u16 slab[ROWS * 512];
  __shared__ __align__(16) u16 phi[ROWS * PSTR];
  __shared__ __align__(16) float red[ROWS * RSTR];  // LN partials [row][wave]{s,t}

  const int f32 = *flagp;
  const int tid = threadIdx.x;
  const int lane = tid & 63, w = tid >> 6;      // 8 waves = 8 groups of 64 ch
  const int r = lane & 15, q = lane >> 4;
  const int i0 = blockIdx.x * 16;               // 16 pairs per block

  f32x4 acc[4][2];                              // [ci: 16-ch group][nt: row half]

  // ---------------- layer 0: [32 x 64] @ W0 -> acc ----------------
#pragma unroll
  for (int ci = 0; ci < 4; ++ci) {
    acc[ci][0] = (f32x4){0.f, 0.f, 0.f, 0.f};
    acc[ci][1] = (f32x4){0.f, 0.f, 0.f, 0.f};
  }
  {
    f16x8 bf0[2][2];
#pragma unroll
    for (int nt = 0; nt < 2; ++nt) {
      int row = nt * 16 + r;                    // even = obs, odd = goals
      const void* base = (row & 1) ? goals : obs;
      long ro = (long)(i0 + (row >> 1)) * 64;
#pragma unroll
      for (int u = 0; u < 2; ++u)
        bf0[nt][u] = load8(base, ro + u * 32 + q * 8, f32);
    }
    const u16* w0base = wT0 + w * 4096;         // 8 frags of 512 u16 per wave
#pragma unroll
    for (int ci = 0; ci < 4; ++ci) {
#pragma unroll
      for (int u = 0; u < 2; ++u) {
        f16x8 af = *(const f16x8*)(w0base + (ci * 2 + u) * 512 + lane * 8);
        acc[ci][0] = __builtin_amdgcn_mfma_f32_16x16x32_f16(af, bf0[0][u], acc[ci][0], 0, 0, 0);
        acc[ci][1] = __builtin_amdgcn_mfma_f32_16x16x32_f16(af, bf0[1][u], acc[ci][1], 0, 0, 0);
      }
    }
  }

  // ---------------- layers 0..2 epilogue + layers 1..3 GEMM ----------------
  for (int l = 0; l <= 3; ++l) {
    if (l > 0) {
      const u16* wp = (l == 1) ? wT1 : (l == 2) ? wT2 : wT3;
      const u16* wbase = wp + w * 32768;        // 64 frags of 512 u16 per wave
#pragma unroll
      for (int ci = 0; ci < 4; ++ci) {
        acc[ci][0] = (f32x4){0.f, 0.f, 0.f, 0.f};
        acc[ci][1] = (f32x4){0.f, 0.f, 0.f, 0.f};
      }
      // register double-buffer over (kq,ci) steps; frag f = ci*16 + kq*4 + u
      f16x8 A[2][4];
#pragma unroll
      for (int u = 0; u < 4; ++u)
        A[0][u] = *(const f16x8*)(wbase + u * 512 + lane * 8);   // ci=0,kq=0
#pragma unroll
      for (int kq = 0; kq < 4; ++kq) {          // K in chunks of 128
        f16x8 bfr[2][4];
        // frag-major slab reads: base + frag*1024B + lane*16B, conflict-free
#pragma unroll
        for (int nt = 0; nt < 2; ++nt)
#pragma unroll
          for (int u = 0; u < 4; ++u)
            bfr[nt][u] = *(const f16x8*)(slab + (nt * 16 + kq * 4 + u) * 512 + lane * 8);
#pragma unroll
        for (int ci = 0; ci < 4; ++ci) {
          const int step = kq * 4 + ci;
          const int cur = step & 1;
          if (step < 15) {
            const int nstep = step + 1;
            const int nci = nstep & 3, nkq = nstep >> 2;
#pragma unroll
            for (int u = 0; u < 4; ++u)
              A[cur ^ 1][u] = *(const f16x8*)(wbase + (nci * 16 + nkq * 4 + u) * 512 + lane * 8);
          }
#pragma unroll
          for (int u = 0; u < 4; ++u) {
            acc[ci][0] = __builtin_amdgcn_mfma_f32_16x16x32_f16(A[cur][u], bfr[0][u], acc[ci][0], 0, 0, 0);
            acc[ci][1] = __builtin_amdgcn_mfma_f32_16x16x32_f16(A[cur][u], bfr[1][u], acc[ci][1], 0, 0, 0);
          }
        }
      }
    }

    if (l < 3) {
      // ---- bias + gelu + LayerNorm -> frag-major slab (fp16) ----
      const void* pb  = (l == 0) ? b0 : (l == 1) ? b1 : b2;
      const void* psl = (l == 0) ? ls0 : (l == 1) ? ls1 : ls2;
      const void* plb = (l == 0) ? lb0 : (l == 1) ? lb1 : lb2;
      float s[2] = {0.f, 0.f}, t[2] = {0.f, 0.f};
#pragma unroll
      for (int ci = 0; ci < 4; ++ci) {
        int cb = w * 64 + ci * 16 + q * 4;
        f32x4 bb = load4p(pb, cb, f32);
#pragma unroll
        for (int nt = 0; nt < 2; ++nt) {
          f32x4 v = acc[ci][nt];
          v.x = gelu_tanh(v.x + bb.x); v.y = gelu_tanh(v.y + bb.y);
          v.z = gelu_tanh(v.z + bb.z); v.w = gelu_tanh(v.w + bb.w);
          acc[ci][nt] = v;
          s[nt] += v.x + v.y + v.z + v.w;
          t[nt] += v.x * v.x + v.y * v.y + v.z * v.z + v.w * v.w;
        }
      }
#pragma unroll
      for (int nt = 0; nt < 2; ++nt) {
        s[nt] += __shfl_xor(s[nt], 16, 64); t[nt] += __shfl_xor(t[nt], 16, 64);
        s[nt] += __shfl_xor(s[nt], 32, 64); t[nt] += __shfl_xor(t[nt], 32, 64);
      }
      if (q == 0) {
        *(float2*)(red + (0 * 16 + r) * RSTR + w * 2) = make_float2(s[0], t[0]);
        *(float2*)(red + (1 * 16 + r) * RSTR + w * 2) = make_float2(s[1], t[1]);
      }
      __syncthreads();   // orders: GEMM slab reads & red writes BEFORE slab writes
      float mean[2], rstd[2];
#pragma unroll
      for (int nt = 0; nt < 2; ++nt) {
        int row = nt * 16 + r;
        float ts = 0.f, tq = 0.f;
#pragma unroll
        for (int p = 0; p < 4; ++p) {
          f32x4 a = *(const f32x4*)(red + row * RSTR + p * 4);
          ts += a.x + a.z; tq += a.y + a.w;
        }
        mean[nt] = ts * (1.f / 512.f);
        rstd[nt] = rsqrtf(tq * (1.f / 512.f) - mean[nt] * mean[nt] + 1e-6f);
      }
#pragma unroll
      for (int ci = 0; ci < 4; ++ci) {
        int cb = w * 64 + ci * 16 + q * 4;
        f32x4 gg = load4p(psl, cb, f32);
        f32x4 hh = load4p(plb, cb, f32);
        // frag-major destination (inverse of the GEMM read mapping)
        int fk = ((cb >> 7) << 2) + ((cb >> 5) & 3);
        int sub = (((cb >> 3) & 3) * 16 + r) * 8 + (cb & 7);
#pragma unroll
        for (int nt = 0; nt < 2; ++nt) {
          f32x4 v = acc[ci][nt];
          ushort4 o;
          o.x = __half_as_ushort(__float2half((v.x - mean[nt]) * rstd[nt] * gg.x + hh.x));
          o.y = __half_as_ushort(__float2half((v.y - mean[nt]) * rstd[nt] * gg.y + hh.y));
          o.z = __half_as_ushort(__float2half((v.z - mean[nt]) * rstd[nt] * gg.z + hh.z));
          o.w = __half_as_ushort(__float2half((v.w - mean[nt]) * rstd[nt] * gg.w + hh.w));
          *(ushort4*)(slab + (nt * 16 + fk) * 512 + sub) = o;
        }
      }
      __syncthreads();
    } else {
      // ---- layer 3: bias only; store phi into its own row-major buffer ----
      __syncthreads();
#pragma unroll
      for (int ci = 0; ci < 4; ++ci) {
        int cb = w * 64 + ci * 16 + q * 4;
        f32x4 bb = load4p(b3, cb, f32);
#pragma unroll
        for (int nt = 0; nt < 2; ++nt) {
          int row = nt * 16 + r;
          f32x4 v = acc[ci][nt];
          ushort4 o;
          o.x = __half_as_ushort(__float2half(v.x + bb.x));
          o.y = __half_as_ushort(__float2half(v.y + bb.y));
          o.z = __half_as_ushort(__float2half(v.z + bb.z));
          o.w = __half_as_ushort(__float2half(v.w + bb.w));
          *(ushort4*)(phi + row * PSTR + cb) = o;
        }
      }
      __syncthreads();   // all phi writes visible before IQE reads
    }
  }

  // ---------------- IQE head: 4-way interleaved shuffle chains ----------------
  // The 8 'it' iterations are independent; processing 4 at once (stage-outer,
  // chain-inner) puts 4 independent ds_bpermute chains in flight per wave,
  // hiding the ~30-40cyc shuffle latency that previously serialized 15 stages.
  {
    const float al = ldp(alphap, 0, f32);
    const float aa = 1.f / (1.f + __expf(-al));
    const int h = lane >> 5, il = lane & 31;    // two components per chain
#pragma unroll
    for (int pv = 0; pv < 2; ++pv) {
      int pL = 2 * w + pv;                      // block-local pair 0..15
      float cs = 0.f, cm = 0.f;
#pragma unroll
      for (int itb = 0; itb < 8; itb += 4) {
        u32 sv[4];
#pragma unroll
        for (int u = 0; u < 4; ++u) {
          int c = 2 * (itb + u) + h;            // component 0..15
          u32 xh = phi[(2 * pL) * PSTR + c * 32 + il];
          u32 yh = phi[(2 * pL + 1) * PSTR + c * 32 + il];
          u32 ex = encH(xh), ey = encH(yh);
          // invalid interval (!(x<y)) -> y = -inf encoding (0x03FF)
          sv[u] = (ex << 16) | ((ex < ey) ? ey : 0x03FFu);
        }
        // bitonic ascending sort of packed (x|y) across each 32-lane half
#pragma unroll
        for (int k = 2; k <= 32; k <<= 1) {
#pragma unroll
          for (int j = k >> 1; j >= 1; j >>= 1) {
            const bool up = ((il & k) == 0) == ((il & j) == 0);
#pragma unroll
            for (int u = 0; u < 4; ++u) {
              u32 so = __shfl_xor(sv[u], j, 64);
              u32 mn = umin32(sv[u], so), mx = umax32(sv[u], so);
              sv[u] = up ? mn : mx;
            }
          }
        }
        // exclusive prefix-max of encoded y in start-sorted order
        u32 ye[4], p[4];
#pragma unroll
        for (int u = 0; u < 4; ++u) {
          ye[u] = sv[u] & 0xFFFFu;
          p[u] = __shfl_up(ye[u], 1, 32);
          if (il == 0) p[u] = 0u;
        }
#pragma unroll
        for (int d = 1; d <= 16; d <<= 1) {
#pragma unroll
          for (int u = 0; u < 4; ++u) {
            u32 t2 = __shfl_up(p[u], d, 32);
            if (il >= d) p[u] = umax32(p[u], t2);
          }
        }
        float contrib[4];
#pragma unroll
        for (int u = 0; u < 4; ++u)
          contrib[u] = fmaxf(0.f, decE(ye[u]) - decE(umax32(sv[u] >> 16, p[u])));
#pragma unroll
        for (int msk = 1; msk <= 16; msk <<= 1)
#pragma unroll
          for (int u = 0; u < 4; ++u)
            contrib[u] += __shfl_xor(contrib[u], msk, 64);
#pragma unroll
        for (int u = 0; u < 4; ++u) {
          cs += contrib[u];
          cm = fmaxf(cm, contrib[u]);
        }
      }
      cs += __shfl_xor(cs, 32, 64);
      cm = fmaxf(cm, __shfl_xor(cm, 32, 64));
      if (lane == 0) {
        float res = aa * (cs * (1.f / 16.f)) + (1.f - aa) * cm;
        if (f32) ((float*)out)[i0 + pL] = res;
        else ((u16*)out)[i0 + pL] = f2bf(res);
      }
    }
  }
}

extern "C" void kernel_launch(void* const* d_in, const int* in_sizes, int n_in,
                              void* d_out, int out_size, void* d_ws, size_t ws_size,
                              hipStream_t stream) {
  (void)in_sizes; (void)n_in; (void)out_size; (void)ws_size;
  const void* obs   = d_in[0];
  const void* goals = d_in[1];
  const void* W0 = d_in[2];
  const void* b0 = d_in[3];
  const void* ls0 = d_in[4];
  const void* lb0 = d_in[5];
  const void* W1 = d_in[6];
  const void* b1 = d_in[7];
  const void* ls1 = d_in[8];
  const void* lb1 = d_in[9];
  const void* W2 = d_in[10];
  const void* b2 = d_in[11];
  const void* ls2 = d_in[12];
  const void* lb2 = d_in[13];
  const void* W3 = d_in[14];
  const void* b3 = d_in[15];
  const void* alpha = d_in[16];

  int* flag = (int*)d_ws;
  u16* wT0 = (u16*)((char*)d_ws + 64);
  u16* wT1 = wT0 + 512 * 64;
  u16* wT2 = wT1 + 512 * 512;
  u16* wT3 = wT2 + 512 * 512;

  detect_dtype<<<1, 64, 0, stream>>>((const u16*)obs, flag);
  // layer0: K=64, nk=2: fshift=3 (4*nk=8 frags/wave), cishift=1, tmask=1
  pack_frag<<<128, 256, 0, stream>>>(W0, wT0, flag, 512 * 64, 3, 1, 1);
  // layers1-3: K=512, nk=16: fshift=6 (64 frags/wave), cishift=4, tmask=15
  pack_frag<<<1024, 256, 0, stream>>>(W1, wT1, flag, 512 * 512, 6, 4, 15);
  pack_frag<<<1024, 256, 0, stream>>>(W2, wT2, flag, 512 * 512, 6, 4, 15);
  pack_frag<<<1024, 256, 0, stream>>>(W3, wT3, flag, 512 * 512, 6, 4, 15);
  gciqe_main<<<8192, 512, 0, stream>>>(obs, goals, wT0, wT1, wT2, wT3,
      b0, b1, b2, b3, ls0, lb0, ls1, lb1, ls2, lb2, alpha, d_out, flag);
}

// Round 12
// 920.957 us; speedup vs baseline: 1.3778x; 1.0011x over previous
//
#include <hip/hip_runtime.h>
#include <hip/hip_bf16.h>
#include <hip/hip_fp16.h>

typedef unsigned short u16;
typedef unsigned int u32;
typedef __attribute__((ext_vector_type(8))) _Float16 f16x8;
typedef __attribute__((ext_vector_type(4))) float f32x4;

#define ROWS 32          // 16 s/g pairs per block
#define RSTR 20          // red stride in floats (16B-aligned, bank-spread)
#define PSTR 520         // phi row stride in u16

__device__ __forceinline__ float bf2f(u16 b) {
  union { u32 u; float f; } c; c.u = ((u32)b) << 16; return c.f;
}
__device__ __forceinline__ u16 f2bf(float f) {
  union { float f; u32 u; } c; c.f = f;
  u32 r = c.u + 0x7FFFu + ((c.u >> 16) & 1u);
  return (u16)(r >> 16);
}
__device__ __forceinline__ float gelu_tanh(float x) {
  // tanh-form gelu == x * sigmoid(2*0.79788456*(x + 0.044715 x^3))
  float x2 = x * x;
  float t = __builtin_fmaf(0.044715f, x2, 1.0f);
  float e = __expf(-1.5957691216057308f * (x * t));
  return x * __builtin_amdgcn_rcpf(1.f + e);
}
// load a scalar param that may be fp32 or bf16
__device__ __forceinline__ float ldp(const void* p, int i, int f32) {
  return f32 ? ((const float*)p)[i] : bf2f(((const u16*)p)[i]);
}
// load 4 consecutive params (fp32 or bf16) vectorized
__device__ __forceinline__ f32x4 load4p(const void* p, int i, int f32) {
  if (f32) return *(const f32x4*)((const float*)p + i);
  ushort4 u = *(const ushort4*)((const u16*)p + i);
  return (f32x4){bf2f(u.x), bf2f(u.y), bf2f(u.z), bf2f(u.w)};
}
// load 8 consecutive elements (fp32 or bf16) as f16x8 (vectorized)
__device__ __forceinline__ f16x8 load8(const void* base, long off, int f32) {
  f16x8 r;
  if (f32) {
    const float4* p = (const float4*)((const float*)base + off);
    float4 a = p[0], b = p[1];
    r[0] = (_Float16)a.x; r[1] = (_Float16)a.y; r[2] = (_Float16)a.z; r[3] = (_Float16)a.w;
    r[4] = (_Float16)b.x; r[5] = (_Float16)b.y; r[6] = (_Float16)b.z; r[7] = (_Float16)b.w;
  } else {
    const u16* p = (const u16*)base + off;
#pragma unroll
    for (int i = 0; i < 8; ++i) r[i] = (_Float16)bf2f(p[i]);
  }
  return r;
}
// monotone (sortable) encoding of fp16 bit patterns, and decode-to-f32
__device__ __forceinline__ u32 encH(u32 h) {
  return (h & 0x8000u) ? (h ^ 0xFFFFu) : (h | 0x8000u);
}
__device__ __forceinline__ float decE(u32 e) {
  u32 h = (e & 0x8000u) ? (e & 0x7FFFu) : (~e & 0xFFFFu);
  return __half2float(__ushort_as_half((u16)h));
}
__device__ __forceinline__ u32 umin32(u32 a, u32 b) { return a < b ? a : b; }
__device__ __forceinline__ u32 umax32(u32 a, u32 b) { return a > b ? a : b; }
// DPP lane-xor for masks 1 (quad_perm[1,0,3,2]=0xB1), 2 (quad_perm[2,3,0,1]=0x4E),
// 8 (row_ror:8=0x128): VALU-latency replacements for ds_bpermute shuffles.
template <int CTRL>
__device__ __forceinline__ u32 dppx(u32 x) {
  return (u32)__builtin_amdgcn_mov_dpp((int)x, CTRL, 0xF, 0xF, false);
}
// shfl_xor with DPP fast path for j in {1,2,8}; j must be compile-time const.
__device__ __forceinline__ u32 lxor(u32 x, int j) {
  if (j == 1) return dppx<0xB1>(x);
  if (j == 2) return dppx<0x4E>(x);
  if (j == 8) return dppx<0x128>(x);
  return (u32)__shfl_xor((int)x, j, 64);
}
__device__ __forceinline__ float lxorf(float x, int j) {
  if (j == 1) return __uint_as_float(dppx<0xB1>(__float_as_uint(x)));
  if (j == 2) return __uint_as_float(dppx<0x4E>(__float_as_uint(x)));
  if (j == 8) return __uint_as_float(dppx<0x128>(__float_as_uint(x)));
  return __shfl_xor(x, j, 64);
}

// one wave: decide whether inputs are fp32 (flag=1) or bf16 (flag=0).
__global__ void detect_dtype(const u16* __restrict__ obs, int* flag) {
  int l = threadIdx.x;
  float v = fabsf(bf2f(obs[2 * l]));
  if (v != v) v = 1e30f;  // NaN pattern also implies fp32
#pragma unroll
  for (int m = 1; m <= 32; m <<= 1) v = fmaxf(v, __shfl_xor(v, m, 64));
  if (l == 0) *flag = (v > 1000.0f) ? 1 : 0;
}

// Pack W [K x 512] into MFMA-fragment-major order (fp16):
// dst[((w*4+ci)*nk + t)*512 + lane*8 + j] = W[k][ch],
//   ch = w*64 + ci*16 + (lane&15), k = t*32 + (lane>>4)*8 + j.
__global__ void pack_frag(const void* __restrict__ src, u16* __restrict__ dst,
                          const int* __restrict__ flag, int total,
                          int fshift, int cishift, int tmask) {
  int id = blockIdx.x * 256 + threadIdx.x;
  if (id >= total) return;
  int j = id & 7;
  int lane = (id >> 3) & 63;
  int fi = id >> 9;
  int w = fi >> fshift;
  int rem = fi & ((1 << fshift) - 1);
  int ci = rem >> cishift;
  int t = rem & tmask;
  int q = lane >> 4, r = lane & 15;
  int ch = w * 64 + ci * 16 + r;
  int k = t * 32 + q * 8 + j;
  float v = ldp(src, k * 512 + ch, *flag);
  dst[id] = __half_as_ushort(__float2half(v));
}

__global__ __launch_bounds__(512, 4) void gciqe_main(
    const void* __restrict__ obs, const void* __restrict__ goals,
    const u16* __restrict__ wT0, const u16* __restrict__ wT1,
    const u16* __restrict__ wT2, const u16* __restrict__ wT3,
    const void* __restrict__ b0, const void* __restrict__ b1,
    const void* __restrict__ b2, const void* __restrict__ b3,
    const void* __restrict__ ls0, const void* __restrict__ lb0,
    const void* __restrict__ ls1, const void* __restrict__ lb1,
    const void* __restrict__ ls2, const void* __restrict__ lb2,
    const void* __restrict__ alphap, void* __restrict__ out,
    const int* __restrict__ flagp)
{
  // slab: layers 0..2 activations, FRAGMENT-MAJOR only (frag f = nt*16+kq*4+u,
  // 32 frags x 512 u16). GEMM reads are slab + f*512 + lane*8: conflict-free.
  // phi: dedicated row-major [32][PSTR] buffer for layer-3 output (IQE input).
  __shared__ __align__(16) u16 slab[ROWS * 512];
  __shared__ __align__(16) u16 phi[ROWS * PSTR];
  __shared__ __align__(16) float red[ROWS * RSTR];  // LN partials [row][wave]{s,t}

  const int f32 = *flagp;
  const int tid = threadIdx.x;
  const int lane = tid & 63, w = tid >> 6;      // 8 waves = 8 groups of 64 ch
  const int r = lane & 15, q = lane >> 4;
  const int i0 = blockIdx.x * 16;               // 16 pairs per block

  f32x4 acc[4][2];                              // [ci: 16-ch group][nt: row half]

  // ---------------- layer 0: [32 x 64] @ W0 -> acc ----------------
#pragma unroll
  for (int ci = 0; ci < 4; ++ci) {
    acc[ci][0] = (f32x4){0.f, 0.f, 0.f, 0.f};
    acc[ci][1] = (f32x4){0.f, 0.f, 0.f, 0.f};
  }
  {
    f16x8 bf0[2][2];
#pragma unroll
    for (int nt = 0; nt < 2; ++nt) {
      int row = nt * 16 + r;                    // even = obs, odd = goals
      const void* base = (row & 1) ? goals : obs;
      long ro = (long)(i0 + (row >> 1)) * 64;
#pragma unroll
      for (int u = 0; u < 2; ++u)
        bf0[nt][u] = load8(base, ro + u * 32 + q * 8, f32);
    }
    const u16* w0base = wT0 + w * 4096;         // 8 frags of 512 u16 per wave
#pragma unroll
    for (int ci = 0; ci < 4; ++ci) {
#pragma unroll
      for (int u = 0; u < 2; ++u) {
        f16x8 af = *(const f16x8*)(w0base + (ci * 2 + u) * 512 + lane * 8);
        acc[ci][0] = __builtin_amdgcn_mfma_f32_16x16x32_f16(af, bf0[0][u], acc[ci][0], 0, 0, 0);
        acc[ci][1] = __builtin_amdgcn_mfma_f32_16x16x32_f16(af, bf0[1][u], acc[ci][1], 0, 0, 0);
      }
    }
  }

  // ---------------- layers 0..2 epilogue + layers 1..3 GEMM ----------------
  for (int l = 0; l <= 3; ++l) {
    if (l > 0) {
      const u16* wp = (l == 1) ? wT1 : (l == 2) ? wT2 : wT3;
      const u16* wbase = wp + w * 32768;        // 64 frags of 512 u16 per wave
#pragma unroll
      for (int ci = 0; ci < 4; ++ci) {
        acc[ci][0] = (f32x4){0.f, 0.f, 0.f, 0.f};
        acc[ci][1] = (f32x4){0.f, 0.f, 0.f, 0.f};
      }
      // A-frag ring of 3, prefetch distance 2: step s = kq*4 + ci uses A[s%3];
      // loads for s+2 issue ~2 MFMA-clusters (~80cy x TLP) before use, covering
      // the ~200-250cy L2 latency that distance-1 left exposed.
      f16x8 A[3][4];
#pragma unroll
      for (int u = 0; u < 4; ++u) {
        A[0][u] = *(const f16x8*)(wbase + u * 512 + lane * 8);          // s=0: f=u
        A[1][u] = *(const f16x8*)(wbase + (16 + u) * 512 + lane * 8);   // s=1: f=16+u
      }
#pragma unroll
      for (int kq = 0; kq < 4; ++kq) {          // K in chunks of 128
        f16x8 bfr[2][4];
        // frag-major slab reads: base + frag*1024B + lane*16B, conflict-free
#pragma unroll
        for (int nt = 0; nt < 2; ++nt)
#pragma unroll
          for (int u = 0; u < 4; ++u)
            bfr[nt][u] = *(const f16x8*)(slab + (nt * 16 + kq * 4 + u) * 512 + lane * 8);
#pragma unroll
        for (int ci = 0; ci < 4; ++ci) {
          const int s = kq * 4 + ci;
          if (s + 2 < 16) {
            const int s2 = s + 2;
            const int nci = s2 & 3, nkq = s2 >> 2;
#pragma unroll
            for (int u = 0; u < 4; ++u)
              A[s2 % 3][u] = *(const f16x8*)(wbase + (nci * 16 + nkq * 4 + u) * 512 + lane * 8);
          }
#pragma unroll
          for (int u = 0; u < 4; ++u) {
            acc[ci][0] = __builtin_amdgcn_mfma_f32_16x16x32_f16(A[s % 3][u], bfr[0][u], acc[ci][0], 0, 0, 0);
            acc[ci][1] = __builtin_amdgcn_mfma_f32_16x16x32_f16(A[s % 3][u], bfr[1][u], acc[ci][1], 0, 0, 0);
          }
        }
      }
    }

    if (l < 3) {
      // ---- bias + gelu + LayerNorm -> frag-major slab (fp16) ----
      const void* pb  = (l == 0) ? b0 : (l == 1) ? b1 : b2;
      const void* psl = (l == 0) ? ls0 : (l == 1) ? ls1 : ls2;
      const void* plb = (l == 0) ? lb0 : (l == 1) ? lb1 : lb2;
      float s[2] = {0.f, 0.f}, t[2] = {0.f, 0.f};
#pragma unroll
      for (int ci = 0; ci < 4; ++ci) {
        int cb = w * 64 + ci * 16 + q * 4;
        f32x4 bb = load4p(pb, cb, f32);
#pragma unroll
        for (int nt = 0; nt < 2; ++nt) {
          f32x4 v = acc[ci][nt];
          v.x = gelu_tanh(v.x + bb.x); v.y = gelu_tanh(v.y + bb.y);
          v.z = gelu_tanh(v.z + bb.z); v.w = gelu_tanh(v.w + bb.w);
          acc[ci][nt] = v;
          s[nt] += v.x + v.y + v.z + v.w;
          t[nt] += v.x * v.x + v.y * v.y + v.z * v.z + v.w * v.w;
        }
      }
#pragma unroll
      for (int nt = 0; nt < 2; ++nt) {
        s[nt] += __shfl_xor(s[nt], 16, 64); t[nt] += __shfl_xor(t[nt], 16, 64);
        s[nt] += __shfl_xor(s[nt], 32, 64); t[nt] += __shfl_xor(t[nt], 32, 64);
      }
      if (q == 0) {
        *(float2*)(red + (0 * 16 + r) * RSTR + w * 2) = make_float2(s[0], t[0]);
        *(float2*)(red + (1 * 16 + r) * RSTR + w * 2) = make_float2(s[1], t[1]);
      }
      __syncthreads();   // orders: GEMM slab reads & red writes BEFORE slab writes
      float mean[2], rstd[2];
#pragma unroll
      for (int nt = 0; nt < 2; ++nt) {
        int row = nt * 16 + r;
        float ts = 0.f, tq = 0.f;
#pragma unroll
        for (int p = 0; p < 4; ++p) {
          f32x4 a = *(const f32x4*)(red + row * RSTR + p * 4);
          ts += a.x + a.z; tq += a.y + a.w;
        }
        mean[nt] = ts * (1.f / 512.f);
        rstd[nt] = rsqrtf(tq * (1.f / 512.f) - mean[nt] * mean[nt] + 1e-6f);
      }
#pragma unroll
      for (int ci = 0; ci < 4; ++ci) {
        int cb = w * 64 + ci * 16 + q * 4;
        f32x4 gg = load4p(psl, cb, f32);
        f32x4 hh = load4p(plb, cb, f32);
        // frag-major destination (inverse of the GEMM read mapping)
        int fk = ((cb >> 7) << 2) + ((cb >> 5) & 3);
        int sub = (((cb >> 3) & 3) * 16 + r) * 8 + (cb & 7);
#pragma unroll
        for (int nt = 0; nt < 2; ++nt) {
          f32x4 v = acc[ci][nt];
          ushort4 o;
          o.x = __half_as_ushort(__float2half((v.x - mean[nt]) * rstd[nt] * gg.x + hh.x));
          o.y = __half_as_ushort(__float2half((v.y - mean[nt]) * rstd[nt] * gg.y + hh.y));
          o.z = __half_as_ushort(__float2half((v.z - mean[nt]) * rstd[nt] * gg.z + hh.z));
          o.w = __half_as_ushort(__float2half((v.w - mean[nt]) * rstd[nt] * gg.w + hh.w));
          *(ushort4*)(slab + (nt * 16 + fk) * 512 + sub) = o;
        }
      }
      __syncthreads();
    } else {
      // ---- layer 3: bias only; store phi into its own row-major buffer ----
      __syncthreads();
#pragma unroll
      for (int ci = 0; ci < 4; ++ci) {
        int cb = w * 64 + ci * 16 + q * 4;
        f32x4 bb = load4p(b3, cb, f32);
#pragma unroll
        for (int nt = 0; nt < 2; ++nt) {
          int row = nt * 16 + r;
          f32x4 v = acc[ci][nt];
          ushort4 o;
          o.x = __half_as_ushort(__float2half(v.x + bb.x));
          o.y = __half_as_ushort(__float2half(v.y + bb.y));
          o.z = __half_as_ushort(__float2half(v.z + bb.z));
          o.w = __half_as_ushort(__float2half(v.w + bb.w));
          *(ushort4*)(phi + row * PSTR + cb) = o;
        }
      }
      __syncthreads();   // all phi writes visible before IQE reads
    }
  }

  // ---------------- IQE head: 4-way interleaved chains + DPP fast shuffles ----
  // 4 independent sort chains in flight per wave (latency hiding); bitonic
  // stages j in {1,2,8} and sum-reduce masks {1,2,8} run as DPP (VALU ~4cy)
  // instead of ds_bpermute (~30-40cy); only j=4 and j=16 remain LDS-pipe.
  {
    const float al = ldp(alphap, 0, f32);
    const float aa = 1.f / (1.f + __expf(-al));
    const int h = lane >> 5, il = lane & 31;    // two components per chain
#pragma unroll
    for (int pv = 0; pv < 2; ++pv) {
      int pL = 2 * w + pv;                      // block-local pair 0..15
      float cs = 0.f, cm = 0.f;
#pragma unroll
      for (int itb = 0; itb < 8; itb += 4) {
        u32 sv[4];
#pragma unroll
        for (int u = 0; u < 4; ++u) {
          int c = 2 * (itb + u) + h;            // component 0..15
          u32 xh = phi[(2 * pL) * PSTR + c * 32 + il];
          u32 yh = phi[(2 * pL + 1) * PSTR + c * 32 + il];
          u32 ex = encH(xh), ey = encH(yh);
          // invalid interval (!(x<y)) -> y = -inf encoding (0x03FF)
          sv[u] = (ex << 16) | ((ex < ey) ? ey : 0x03FFu);
        }
        // bitonic ascending sort of packed (x|y) across each 32-lane half
#pragma unroll
        for (int k = 2; k <= 32; k <<= 1) {
#pragma unroll
          for (int j = k >> 1; j >= 1; j >>= 1) {
            const bool up = ((il & k) == 0) == ((il & j) == 0);
#pragma unroll
            for (int u = 0; u < 4; ++u) {
              u32 so = lxor(sv[u], j);
              u32 mn = umin32(sv[u], so), mx = umax32(sv[u], so);
              sv[u] = up ? mn : mx;
            }
          }
        }
        // exclusive prefix-max of encoded y in start-sorted order
        u32 ye[4], p[4];
#pragma unroll
        for (int u = 0; u < 4; ++u) {
          ye[u] = sv[u] & 0xFFFFu;
          p[u] = __shfl_up(ye[u], 1, 32);
          if (il == 0) p[u] = 0u;
        }
#pragma unroll
        for (int d = 1; d <= 16; d <<= 1) {
#pragma unroll
          for (int u = 0; u < 4; ++u) {
            u32 t2 = __shfl_up(p[u], d, 32);
            if (il >= d) p[u] = umax32(p[u], t2);
          }
        }
        float contrib[4];
#pragma unroll
        for (int u = 0; u < 4; ++u)
          contrib[u] = fmaxf(0.f, decE(ye[u]) - decE(umax32(sv[u] >> 16, p[u])));
#pragma unroll
        for (int msk = 1; msk <= 16; msk <<= 1)
#pragma unroll
          for (int u = 0; u < 4; ++u)
            contrib[u] += lxorf(contrib[u], msk);
#pragma unroll
        for (int u = 0; u < 4; ++u) {
          cs += contrib[u];
          cm = fmaxf(cm, contrib[u]);
        }
      }
      cs += __shfl_xor(cs, 32, 64);
      cm = fmaxf(cm, __shfl_xor(cm, 32, 64));
      if (lane == 0) {
        float res = aa * (cs * (1.f / 16.f)) + (1.f - aa) * cm;
        if (f32) ((float*)out)[i0 + pL] = res;
        else ((u16*)out)[i0 + pL] = f2bf(res);
      }
    }
  }
}

extern "C" void kernel_launch(void* const* d_in, const int* in_sizes, int n_in,
                              void* d_out, int out_size, void* d_ws, size_t ws_size,
                              hipStream_t stream) {
  (void)in_sizes; (void)n_in; (void)out_size; (void)ws_size;
  const void* obs   = d_in[0];
  const void* goals = d_in[1];
  const void* W0 = d_in[2];
  const void* b0 = d_in[3];
  const void* ls0 = d_in[4];
  const void* lb0 = d_in[5];
  const void* W1 = d_in[6];
  const void* b1 = d_in[7];
  const void* ls1 = d_in[8];
  const void* lb1 = d_in[9];
  const void* W2 = d_in[10];
  const void* b2 = d_in[11];
  const void* ls2 = d_in[12];
  const void* lb2 = d_in[13];
  const void* W3 = d_in[14];
  const void* b3 = d_in[15];
  const void* alpha = d_in[16];

  int* flag = (int*)d_ws;
  u16* wT0 = (u16*)((char*)d_ws + 64);
  u16* wT1 = wT0 + 512 * 64;
  u16* wT2 = wT1 + 512 * 512;
  u16* wT3 = wT2 + 512 * 512;

  detect_dtype<<<1, 64, 0, stream>>>((const u16*)obs, flag);
  // layer0: K=64, nk=2: fshift=3 (4*nk=8 frags/wave), cishift=1, tmask=1
  pack_frag<<<128, 256, 0, stream>>>(W0, wT0, flag, 512 * 64, 3, 1, 1);
  // layers1-3: K=512, nk=16: fshift=6 (64 frags/wave), cishift=4, tmask=15
  pack_frag<<<1024, 256, 0, stream>>>(W1, wT1, flag, 512 * 512, 6, 4, 15);
  pack_frag<<<1024, 256, 0, stream>>>(W2, wT2, flag, 512 * 512, 6, 4, 15);
  pack_frag<<<1024, 256, 0, stream>>>(W3, wT3, flag, 512 * 512, 6, 4, 15);
  gciqe_main<<<8192, 512, 0, stream>>>(obs, goals, wT0, wT1, wT2, wT3,
      b0, b1, b2, b3, ls0, lb0, ls1, lb1, ls2, lb2, alpha, d_out, flag);
}